// Round 1
// baseline (244.618 us; speedup 1.0000x reference)
//
#include <hip/hip_runtime.h>
#include <stdint.h>

// Problem constants (SelfAttention: B=8, C=512, C8=64, W=2048)
#define B_  8
#define C_  512
#define CO_ 64
#define W_  2048
#define R_  640   // stacked projection rows: 64 q + 64 k + 512 v

typedef float f32x4 __attribute__((ext_vector_type(4)));
typedef __bf16 bf16x8 __attribute__((ext_vector_type(8)));
typedef unsigned short u16;
typedef u16 u16x8 __attribute__((ext_vector_type(8)));
typedef u16 u16x4 __attribute__((ext_vector_type(4)));

static __device__ __forceinline__ u16 f2b(float f){
  union { float f; unsigned u; } v; v.f = f;
  unsigned r = v.u + 0x7FFFu + ((v.u >> 16) & 1u);  // RNE
  return (u16)(r >> 16);
}
static __device__ __forceinline__ bf16x8 ldb(const u16* p){
  return __builtin_bit_cast(bf16x8, *(const u16x8*)p);
}
static __device__ __forceinline__ f32x4 mfma16(bf16x8 a, bf16x8 b, f32x4 c){
  return __builtin_amdgcn_mfma_f32_16x16x32_bf16(a, b, c, 0, 0, 0);
}

// ---------------- K0: stack + cast weights/bias to bf16 ----------------
__global__ __launch_bounds__(256) void prep_w(
    const float* __restrict__ Wq, const float* __restrict__ bq,
    const float* __restrict__ Wk, const float* __restrict__ bk,
    const float* __restrict__ Wv, const float* __restrict__ bv,
    u16* __restrict__ Wall, float* __restrict__ ball){
  int e = blockIdx.x * 256 + threadIdx.x;
  if (e < R_ * C_){
    int r = e >> 9, c = e & (C_ - 1);
    float w;
    if (r < 64)       w = Wq[r * C_ + c];
    else if (r < 128) w = Wk[(r - 64) * C_ + c];
    else              w = Wv[(r - 128) * C_ + c];
    Wall[e] = f2b(w);
  }
  if (e < R_){
    float bb;
    if (e < 64)       bb = bq[e];
    else if (e < 128) bb = bk[e - 64];
    else              bb = bv[e - 128];
    ball[e] = bb;
  }
}

// ---------------- K1: x [b][c][w] f32 -> xbT [b][w][c] bf16 ----------------
__global__ __launch_bounds__(256) void xpose(const float* __restrict__ x,
                                             u16* __restrict__ xbT){
  __shared__ float t[32][33];
  int b = blockIdx.z, c0 = blockIdx.y * 32, w0 = blockIdx.x * 32;
  int tx = threadIdx.x & 31, ty = threadIdx.x >> 5;   // ty 0..7
  const float* xb = x + (size_t)b * C_ * W_;
  #pragma unroll
  for (int k = 0; k < 4; k++)
    t[ty + k * 8][tx] = xb[(size_t)(c0 + ty + k * 8) * W_ + w0 + tx];
  __syncthreads();
  u16* ob = xbT + (size_t)b * W_ * C_;
  #pragma unroll
  for (int k = 0; k < 4; k++)
    ob[(size_t)(w0 + ty + k * 8) * C_ + c0 + tx] = f2b(t[tx][ty + k * 8]);
}

// ---------------- K2: fused projection GEMM ----------------
// Y[r][w] = sum_c Wall[r][c] * x[c][w] + ball[r], per batch.
// Outputs: r<64 -> q_t[w][r] ; 64<=r<128 -> kT[w][r-64] ; else v[r-128][w]
#define PADW 40
__global__ __launch_bounds__(256) void gemm_proj(
    const u16* __restrict__ Wall, const float* __restrict__ ball,
    const u16* __restrict__ xbT, u16* __restrict__ qt,
    u16* __restrict__ ktp, u16* __restrict__ vn){
  __shared__ u16 at[64][PADW];
  __shared__ u16 bt[64][PADW];
  int b = blockIdx.z;
  int m0 = blockIdx.y * 64, n0 = blockIdx.x * 64;
  int tid = threadIdx.x, lane = tid & 63, wid = tid >> 6;
  int wm = wid >> 1, wn = wid & 1;
  int g = lane >> 4, r = lane & 15;
  const u16* xb = xbT + (size_t)b * W_ * C_;
  f32x4 acc[2][2] = {};
  int srow = tid >> 2, sseg = (tid & 3) * 8;
  for (int kk = 0; kk < 16; kk++){
    int c0 = kk * 32;
    *(u16x8*)&at[srow][sseg] = *(const u16x8*)&Wall[(size_t)(m0 + srow) * C_ + c0 + sseg];
    *(u16x8*)&bt[srow][sseg] = *(const u16x8*)&xb[(size_t)(n0 + srow) * C_ + c0 + sseg];
    __syncthreads();
    bf16x8 a0 = ldb(&at[wm * 32 +  0 + r][g * 8]);
    bf16x8 a1 = ldb(&at[wm * 32 + 16 + r][g * 8]);
    bf16x8 b0 = ldb(&bt[wn * 32 +  0 + r][g * 8]);
    bf16x8 b1 = ldb(&bt[wn * 32 + 16 + r][g * 8]);
    acc[0][0] = mfma16(a0, b0, acc[0][0]);
    acc[0][1] = mfma16(a0, b1, acc[0][1]);
    acc[1][0] = mfma16(a1, b0, acc[1][0]);
    acc[1][1] = mfma16(a1, b1, acc[1][1]);
    __syncthreads();
  }
  // epilogue: bias + store in attention layouts
  #pragma unroll
  for (int i = 0; i < 2; i++){
    #pragma unroll
    for (int n = 0; n < 2; n++){
      int rbase = m0 + wm * 32 + i * 16 + g * 4;
      int wcol  = n0 + wn * 32 + n * 16 + r;
      if (m0 < 128){
        u16* base = (m0 == 0 ? qt : ktp) + (size_t)b * W_ * CO_;
        u16x4 pk;
        #pragma unroll
        for (int t = 0; t < 4; t++) pk[t] = f2b(acc[i][n][t] + ball[rbase + t]);
        *(u16x4*)&base[(size_t)wcol * CO_ + (rbase & 63)] = pk;
      } else {
        u16* vb = vn + (size_t)b * C_ * W_;
        #pragma unroll
        for (int t = 0; t < 4; t++)
          vb[(size_t)(rbase + t - 128) * W_ + wcol] = f2b(acc[i][n][t] + ball[rbase + t]);
      }
    }
  }
}

// ---------------- K3: flash attention + epilogue ----------------
// Block: (b, 64 q-rows). 8 waves: wi in {0,1} (32 rows), wc in {0..3} (128 cols of C).
__global__ __launch_bounds__(512) void attn(
    const u16* __restrict__ qt, const u16* __restrict__ ktp,
    const u16* __restrict__ vn, const float* __restrict__ x,
    const float* __restrict__ gamma, float* __restrict__ out){
  __shared__ u16 kt_s[64][72];
  __shared__ float s_s[64][65];
  __shared__ u16 p_s[64][72];
  __shared__ float m_s[64], l_s[64], a_s[64];
  int b = blockIdx.y;
  int i0 = blockIdx.x * 64;
  int tid = threadIdx.x, lane = tid & 63, wid = tid >> 6;
  int wi = wid >> 2, wc = wid & 3;
  int g = lane >> 4, r = lane & 15;
  if (tid < 64){ m_s[tid] = -1e30f; l_s[tid] = 0.f; }
  const u16* qtb = qt  + (size_t)b * W_ * CO_;
  const u16* ktb = ktp + (size_t)b * W_ * CO_;
  const u16* vnb = vn  + (size_t)b * C_ * W_;
  // hoist Q fragments (A operand of S): rows i0+wi*32+i*16+r, cols o
  bf16x8 aq[2][2];
  #pragma unroll
  for (int i = 0; i < 2; i++)
    #pragma unroll
    for (int ko = 0; ko < 2; ko++)
      aq[i][ko] = ldb(&qtb[(size_t)(i0 + wi * 32 + i * 16 + r) * CO_ + ko * 32 + g * 8]);
  f32x4 acc[2][8] = {};
  int srow = tid >> 3, sseg = (tid & 7) * 8;
  for (int jt = 0; jt < 32; jt++){
    int j0 = jt * 64;
    // stage kT tile [64 j][64 o]
    *(u16x8*)&kt_s[srow][sseg] = *(const u16x8*)&ktb[(size_t)(j0 + srow) * CO_ + sseg];
    __syncthreads();
    // S = q . k : wave computes 32(i) x 16(j) slice at j-range wc*16
    {
      bf16x8 bk0 = ldb(&kt_s[wc * 16 + r][ 0 + g * 8]);
      bf16x8 bk1 = ldb(&kt_s[wc * 16 + r][32 + g * 8]);
      #pragma unroll
      for (int i = 0; i < 2; i++){
        f32x4 s = {};
        s = mfma16(aq[i][0], bk0, s);
        s = mfma16(aq[i][1], bk1, s);
        #pragma unroll
        for (int t = 0; t < 4; t++)
          s_s[wi * 32 + i * 16 + g * 4 + t][wc * 16 + r] = s[t];
      }
    }
    __syncthreads();
    // wave-parallel online softmax: 8 threads per row
    {
      float vv[8]; float mx = -1e30f;
      #pragma unroll
      for (int u = 0; u < 8; u++){ vv[u] = s_s[srow][sseg + u]; mx = fmaxf(mx, vv[u]); }
      mx = fmaxf(mx, __shfl_xor(mx, 1));
      mx = fmaxf(mx, __shfl_xor(mx, 2));
      mx = fmaxf(mx, __shfl_xor(mx, 4));
      float mold = m_s[srow];
      float mnew = fmaxf(mold, mx);
      float al = __expf(mold - mnew);
      float sum = 0.f;
      u16x8 pv;
      #pragma unroll
      for (int u = 0; u < 8; u++){ float p = __expf(vv[u] - mnew); sum += p; pv[u] = f2b(p); }
      sum += __shfl_xor(sum, 1);
      sum += __shfl_xor(sum, 2);
      sum += __shfl_xor(sum, 4);
      *(u16x8*)&p_s[srow][sseg] = pv;
      if ((tid & 7) == 0){ m_s[srow] = mnew; l_s[srow] = l_s[srow] * al + sum; a_s[srow] = al; }
    }
    __syncthreads();
    // rescale accumulators by alpha(row)
    #pragma unroll
    for (int i = 0; i < 2; i++){
      f32x4 alv;
      #pragma unroll
      for (int t = 0; t < 4; t++) alv[t] = a_s[wi * 32 + i * 16 + g * 4 + t];
      #pragma unroll
      for (int n = 0; n < 8; n++)
        #pragma unroll
        for (int t = 0; t < 4; t++) acc[i][n][t] *= alv[t];
    }
    // PV: acc[i][n] += P[i][j] * v[c][j]
    #pragma unroll
    for (int kj = 0; kj < 2; kj++){
      bf16x8 ap0 = ldb(&p_s[wi * 32 +  0 + r][kj * 32 + g * 8]);
      bf16x8 ap1 = ldb(&p_s[wi * 32 + 16 + r][kj * 32 + g * 8]);
      #pragma unroll
      for (int n = 0; n < 8; n++){
        bf16x8 bv = ldb(&vnb[(size_t)(wc * 128 + n * 16 + r) * W_ + j0 + kj * 32 + g * 8]);
        acc[0][n] = mfma16(ap0, bv, acc[0][n]);
        acc[1][n] = mfma16(ap1, bv, acc[1][n]);
      }
    }
    __syncthreads();
  }
  // epilogue: out = gamma * (acc/l) + x  (rows=i contiguous -> float4)
  float gm = gamma[0];
  const float* xb = x + (size_t)b * C_ * W_;
  float* ob = out + (size_t)b * C_ * W_;
  #pragma unroll
  for (int i = 0; i < 2; i++){
    f32x4 inv;
    #pragma unroll
    for (int t = 0; t < 4; t++) inv[t] = 1.f / l_s[wi * 32 + i * 16 + g * 4 + t];
    int irow = i0 + wi * 32 + i * 16 + g * 4;
    #pragma unroll
    for (int n = 0; n < 8; n++){
      int c = wc * 128 + n * 16 + r;
      f32x4 xv = *(const f32x4*)&xb[(size_t)c * W_ + irow];
      f32x4 ov;
      #pragma unroll
      for (int t = 0; t < 4; t++) ov[t] = gm * (acc[i][n][t] * inv[t]) + xv[t];
      *(f32x4*)&ob[(size_t)c * W_ + irow] = ov;
    }
  }
}

extern "C" void kernel_launch(void* const* d_in, const int* in_sizes, int n_in,
                              void* d_out, int out_size, void* d_ws, size_t ws_size,
                              hipStream_t stream) {
  const float* x     = (const float*)d_in[0];
  const float* Wq    = (const float*)d_in[1];
  const float* bq    = (const float*)d_in[2];
  const float* Wk    = (const float*)d_in[3];
  const float* bk    = (const float*)d_in[4];
  const float* Wv    = (const float*)d_in[5];
  const float* bv    = (const float*)d_in[6];
  const float* gamma = (const float*)d_in[7];
  float* out = (float*)d_out;
  char* ws = (char*)d_ws;
  // workspace layout (~38.4 MB total)
  u16*   Wall = (u16*)  (ws + 0);         // 640*512*2        = 655360
  float* ball = (float*)(ws + 655360);    // 640*4            = 2560
  u16*   xbT  = (u16*)  (ws + 657920);    // 8*2048*512*2     = 16777216
  u16*   qt   = (u16*)  (ws + 17435136);  // 8*2048*64*2      = 2097152
  u16*   ktp  = (u16*)  (ws + 19532288);  // 8*2048*64*2      = 2097152
  u16*   vn   = (u16*)  (ws + 21629440);  // 8*512*2048*2     = 16777216

  prep_w<<<dim3(1280), dim3(256), 0, stream>>>(Wq, bq, Wk, bk, Wv, bv, Wall, ball);
  xpose<<<dim3(64, 16, 8), dim3(256), 0, stream>>>(x, xbT);
  gemm_proj<<<dim3(32, 10, 8), dim3(256), 0, stream>>>(Wall, ball, xbT, qt, ktp, vn);
  attn<<<dim3(32, 8), dim3(512), 0, stream>>>(qt, ktp, vn, x, gamma, out);
}